// Round 1
// baseline (19407.512 us; speedup 1.0000x reference)
//
#include <hip/hip_runtime.h>
#include <cstdint>
#include <cstddef>

// CMAlign forward, fp32 correctness-first implementation.
// Shapes: B=64 (32 visible + 32 thermal), C=2048, Cq=512, H=24, W=12, HW=288.
// Pipeline: mask -> conv(q), conv(k) -> inv-norms -> [pos: sim/softmax/comask/warp+recon+d_ap]
//           -> [neg: sim/softmax/warp+d_an] -> triplet loss.
// ws usage: ~97.2 MB.

namespace {
constexpr int kB    = 64;
constexpr int kHalf = 32;
constexpr int kC    = 2048;
constexpr int kCQ   = 512;
constexpr int kH    = 24;
constexpr int kW    = 12;
constexpr int kHW   = 288;
constexpr float kTemp = 50.0f;
}

__device__ __forceinline__ const float* feat_base(const float* fv, const float* ft, int b) {
  return (b < kHalf) ? (fv + (size_t)b * kC * kHW)
                     : (ft + (size_t)(b - kHalf) * kC * kHW);
}

__global__ void zero_kernel(float* __restrict__ p, int n) {
  int i = blockIdx.x * 256 + threadIdx.x;
  if (i < n) p[i] = 0.f;
}

// ---------------- mask: per-sample min-max normalized channel L2 norm ----------------
__global__ __launch_bounds__(320) void mask_kernel(const float* __restrict__ fv,
                                                   const float* __restrict__ ft,
                                                   float* __restrict__ mask) {
  int b = blockIdx.x;
  int t = threadIdx.x;
  const float* fb = feat_base(fv, ft, b);
  float n = 0.f;
  if (t < kHW) {
    float s = 0.f;
    for (int c = 0; c < kC; ++c) { float v = fb[(size_t)c * kHW + t]; s += v * v; }
    n = sqrtf(s);
  }
  __shared__ float sh[320];
  sh[t] = (t < kHW) ? n : 3.4e38f;
  __syncthreads();
  float mn;
  {
    float m = 3.4e38f;
    if (t < 64) {
      for (int i = t; i < 320; i += 64) m = fminf(m, sh[i]);
      for (int off = 32; off; off >>= 1) m = fminf(m, __shfl_xor(m, off));
    }
    __syncthreads();
    if (t == 0) sh[0] = m;
    __syncthreads();
    mn = sh[0];
    __syncthreads();
  }
  sh[t] = (t < kHW) ? n : -3.4e38f;
  __syncthreads();
  float mx;
  {
    float m = -3.4e38f;
    if (t < 64) {
      for (int i = t; i < 320; i += 64) m = fmaxf(m, sh[i]);
      for (int off = 32; off; off >>= 1) m = fmaxf(m, __shfl_xor(m, off));
    }
    __syncthreads();
    if (t == 0) sh[0] = m;
    __syncthreads();
    mx = sh[0];
  }
  if (t < kHW) mask[b * kHW + t] = (n - mn) / ((mx - mn) + 1e-12f);
}

// ---------------- 3x3 conv, pad=1, fp32. 2 samples + 16 out-channels per block ----------------
#define ICC 8
__global__ __launch_bounds__(320) void conv_kernel(const float* __restrict__ fv,
                                                   const float* __restrict__ ft,
                                                   const float* __restrict__ w,
                                                   const float* __restrict__ bias,
                                                   float* __restrict__ outp) {
  int oc0 = blockIdx.x * 16;
  int b0  = blockIdx.y * 2;
  int t   = threadIdx.x;
  __shared__ float lds[2][ICC][26][16];
  const float* f0 = feat_base(fv, ft, b0);
  const float* f1 = feat_base(fv, ft, b0 + 1);
  int p = t;
  int y = p / 12;
  int x = p - y * 12;
  float acc0[16], acc1[16];
#pragma unroll
  for (int oc = 0; oc < 16; ++oc) { acc0[oc] = 0.f; acc1[oc] = 0.f; }

#pragma unroll 1
  for (int ic0 = 0; ic0 < kC; ic0 += ICC) {
    __syncthreads();
    for (int li = t; li < 2 * ICC * 26 * 16; li += 320) {
      int s  = li / (ICC * 26 * 16);
      int r1 = li - s * (ICC * 26 * 16);
      int ic = r1 / (26 * 16);
      int r2 = r1 - ic * (26 * 16);
      int yy = r2 >> 4;
      int xx = r2 & 15;
      int gy = yy - 1, gx = xx - 1;
      float v = 0.f;
      if (gy >= 0 && gy < kH && gx >= 0 && gx < kW) {
        const float* fb = s ? f1 : f0;
        v = fb[(size_t)(ic0 + ic) * kHW + gy * kW + gx];
      }
      lds[s][ic][yy][xx] = v;
    }
    __syncthreads();
    if (p < kHW) {
#pragma unroll 1
      for (int ic = 0; ic < ICC; ++ic) {
        float xv0[9], xv1[9];
#pragma unroll
        for (int r = 0; r < 3; ++r)
#pragma unroll
          for (int s2 = 0; s2 < 3; ++s2) {
            xv0[r * 3 + s2] = lds[0][ic][y + r][x + s2];
            xv1[r * 3 + s2] = lds[1][ic][y + r][x + s2];
          }
#pragma unroll
        for (int oc = 0; oc < 16; ++oc) {
          const float* wp = w + ((size_t)(oc0 + oc) * kC + (ic0 + ic)) * 9;
#pragma unroll
          for (int j = 0; j < 9; ++j) {
            float wv = wp[j];
            acc0[oc] = fmaf(wv, xv0[j], acc0[oc]);
            acc1[oc] = fmaf(wv, xv1[j], acc1[oc]);
          }
        }
      }
    }
  }
  if (p < kHW) {
#pragma unroll
    for (int oc = 0; oc < 16; ++oc) {
      float bz = bias[oc0 + oc];
      outp[((size_t)b0 * kCQ + oc0 + oc) * kHW + p]       = acc0[oc] + bz;
      outp[((size_t)(b0 + 1) * kCQ + oc0 + oc) * kHW + p] = acc1[oc] + bz;
    }
  }
}

// ---------------- per-(b,pos) inverse L2 norm over the 512 projected channels ----------------
__global__ __launch_bounds__(320) void norminv_kernel(const float* __restrict__ fq,
                                                      const float* __restrict__ fk,
                                                      float* __restrict__ qinv,
                                                      float* __restrict__ kinv) {
  int b = blockIdx.x;
  int z = blockIdx.y;
  const float* src = z ? fk : fq;
  float* dst       = z ? kinv : qinv;
  int t = threadIdx.x;
  if (t >= kHW) return;
  const float* sb = src + (size_t)b * kCQ * kHW;
  float s = 0.f;
  for (int c = 0; c < kCQ; ++c) { float v = sb[(size_t)c * kHW + t]; s += v * v; }
  float n = sqrtf(s);
  dst[b * kHW + t] = 1.f / fmaxf(n, 1e-12f);
}

// ---------------- sim logits: 50 * (fq_n . fk_n); thread = k, acc over 32 q ----------------
__global__ __launch_bounds__(320) void sim_kernel(const float* __restrict__ fq,
                                                  const float* __restrict__ fk,
                                                  const float* __restrict__ qinv,
                                                  const float* __restrict__ kinv,
                                                  const int* __restrict__ idx,
                                                  float* __restrict__ logits) {
  int b  = blockIdx.y;
  int q0 = blockIdx.x * 32;
  int t  = threadIdx.x;
  if (t >= kHW) return;
  int tb = idx[b];
  const float* fqb = fq + (size_t)b * kCQ * kHW + q0;
  const float* fkb = fk + (size_t)tb * kCQ * kHW;
  float acc[32];
#pragma unroll
  for (int q = 0; q < 32; ++q) acc[q] = 0.f;
#pragma unroll 1
  for (int c = 0; c < kCQ; ++c) {
    float kv = fkb[(size_t)c * kHW + t];
#pragma unroll
    for (int q = 0; q < 32; ++q) acc[q] = fmaf(fqb[(size_t)c * kHW + q], kv, acc[q]);
  }
  float ks = kinv[tb * kHW + t];
#pragma unroll
  for (int q = 0; q < 32; ++q) {
    float lg = kTemp * qinv[b * kHW + q0 + q] * ks * acc[q];
    logits[((size_t)b * kHW + q0 + q) * kHW + t] = lg;
  }
}

// ---------------- row softmax over k (in place) ----------------
__global__ __launch_bounds__(320) void softmax_kernel(float* __restrict__ pr) {
  int row = blockIdx.x;  // b*HW + q
  int t   = threadIdx.x;
  float* rp = pr + (size_t)row * kHW;
  float v = (t < kHW) ? rp[t] : -3.4e38f;
  __shared__ float sh[5];
  int wv = t >> 6, l = t & 63;
  float m = v;
  for (int off = 32; off; off >>= 1) m = fmaxf(m, __shfl_xor(m, off));
  if (l == 0) sh[wv] = m;
  __syncthreads();
  if (t == 0) { float mm = sh[0]; for (int i = 1; i < 5; ++i) mm = fmaxf(mm, sh[i]); sh[0] = mm; }
  __syncthreads();
  m = sh[0];
  float e = (t < kHW) ? __expf(v - m) : 0.f;
  float s = e;
  for (int off = 32; off; off >>= 1) s += __shfl_xor(s, off);
  __syncthreads();
  if (l == 0) sh[wv] = s;
  __syncthreads();
  if (t == 0) { float ss = sh[0]; for (int i = 1; i < 5; ++i) ss += sh[i]; sh[0] = ss; }
  __syncthreads();
  s = sh[0];
  if (t < kHW) rp[t] = e / s;
}

// ---------------- comask: mask[q] * sum_k pr[q,k]*mask_t[k], min-max normalized per b ----------------
__global__ __launch_bounds__(320) void comask_kernel(const float* __restrict__ pr,
                                                     const float* __restrict__ mask,
                                                     const int* __restrict__ idx,
                                                     float* __restrict__ comask) {
  int b = blockIdx.x;
  int t = threadIdx.x;
  int tb = idx[b];
  __shared__ float mt[kHW];
  __shared__ float cm[kHW];
  __shared__ float red[320];
  if (t < kHW) mt[t] = mask[tb * kHW + t];
  __syncthreads();
  int wv = t >> 6, l = t & 63;
  for (int q = wv; q < kHW; q += 5) {
    const float* prow = pr + ((size_t)b * kHW + q) * kHW;
    float s = 0.f;
    for (int k = l; k < kHW; k += 64) s += prow[k] * mt[k];
    for (int off = 32; off; off >>= 1) s += __shfl_xor(s, off);
    if (l == 0) cm[q] = mask[b * kHW + q] * s;
  }
  __syncthreads();
  float v = (t < kHW) ? cm[t] : 0.f;
  red[t] = (t < kHW) ? v : 3.4e38f;
  __syncthreads();
  float mn;
  {
    float m = 3.4e38f;
    if (t < 64) {
      for (int i = t; i < 320; i += 64) m = fminf(m, red[i]);
      for (int off = 32; off; off >>= 1) m = fminf(m, __shfl_xor(m, off));
    }
    __syncthreads();
    if (t == 0) red[0] = m;
    __syncthreads();
    mn = red[0];
    __syncthreads();
  }
  red[t] = (t < kHW) ? v : -3.4e38f;
  __syncthreads();
  float mx;
  {
    float m = -3.4e38f;
    if (t < 64) {
      for (int i = t; i < 320; i += 64) m = fmaxf(m, red[i]);
      for (int off = 32; off; off >>= 1) m = fmaxf(m, __shfl_xor(m, off));
    }
    __syncthreads();
    if (t == 0) red[0] = m;
    __syncthreads();
    mx = red[0];
  }
  if (t < kHW) comask[b * kHW + t] = (v - mn) / ((mx - mn) + 1e-12f);
}

// ---------------- warp GEMM: W[c,q] = sum_k tgt[c,k]*pr[q,k]; recon + dist^2 accumulation ----------------
__global__ __launch_bounds__(256) void warp_kernel(const float* __restrict__ fv,
                                                   const float* __restrict__ ft,
                                                   const float* __restrict__ pr,
                                                   const float* __restrict__ maskp,
                                                   const int* __restrict__ idx,
                                                   float* __restrict__ outp,
                                                   float* __restrict__ dsq,
                                                   int write_out) {
  int b  = blockIdx.z;
  int c0 = blockIdx.y * 64;
  int q0 = blockIdx.x * 64;
  int t  = threadIdx.x;
  int tc = t & 15;   // q direction (4 consecutive q per thread)
  int tq = t >> 4;   // c direction (4 consecutive c per thread)
  int tb = idx[b];
  const float* tgt = feat_base(fv, ft, tb);
  const float* fb  = feat_base(fv, ft, b);
  __shared__ float As[16][68];  // [k][c]
  __shared__ float Bs[16][68];  // [k][q]
  float acc[4][4];
#pragma unroll
  for (int i = 0; i < 4; ++i)
#pragma unroll
    for (int j = 0; j < 4; ++j) acc[i][j] = 0.f;

#pragma unroll 1
  for (int k0 = 0; k0 < kHW; k0 += 16) {
    __syncthreads();
    for (int li = t; li < 1024; li += 256) {
      int cc = li >> 4, kk = li & 15;
      As[kk][cc] = tgt[(size_t)(c0 + cc) * kHW + k0 + kk];
    }
    for (int li = t; li < 1024; li += 256) {
      int qq = li >> 4, kk = li & 15;
      Bs[kk][qq] = (q0 + qq < kHW) ? pr[((size_t)b * kHW + q0 + qq) * kHW + k0 + kk] : 0.f;
    }
    __syncthreads();
#pragma unroll
    for (int kk = 0; kk < 16; ++kk) {
      const float4 a4 = *reinterpret_cast<const float4*>(&As[kk][tq * 4]);
      const float4 b4 = *reinterpret_cast<const float4*>(&Bs[kk][tc * 4]);
      float av[4] = {a4.x, a4.y, a4.z, a4.w};
      float bv[4] = {b4.x, b4.y, b4.z, b4.w};
#pragma unroll
      for (int i = 0; i < 4; ++i)
#pragma unroll
        for (int j = 0; j < 4; ++j) acc[i][j] = fmaf(av[i], bv[j], acc[i][j]);
    }
  }

  int qbase = q0 + tc * 4;
  float psum[4] = {0.f, 0.f, 0.f, 0.f};
  if (qbase < kHW) {
    float mj[4];
#pragma unroll
    for (int j = 0; j < 4; ++j) mj[j] = maskp[b * kHW + qbase + j];
#pragma unroll
    for (int i = 0; i < 4; ++i) {
      int c = c0 + tq * 4 + i;
      const float4 f4 = *reinterpret_cast<const float4*>(&fb[(size_t)c * kHW + qbase]);
      float fvv[4] = {f4.x, f4.y, f4.z, f4.w};
      float o[4];
#pragma unroll
      for (int j = 0; j < 4; ++j) {
        float Wv = acc[i][j];
        float d  = mj[j] * (fvv[j] - Wv) + 1e-6f;
        psum[j] += d * d;
        o[j] = mj[j] * Wv + (1.f - mj[j]) * fvv[j];
      }
      if (write_out) {
        float4 o4 = make_float4(o[0], o[1], o[2], o[3]);
        *reinterpret_cast<float4*>(&outp[((size_t)b * kC + c) * kHW + qbase]) = o4;
      }
    }
  }
#pragma unroll
  for (int j = 0; j < 4; ++j) {
    float s = psum[j];
    s += __shfl_xor(s, 16);
    s += __shfl_xor(s, 32);
    if (((t >> 4) & 3) == 0 && qbase < kHW)
      atomicAdd(&dsq[b * kHW + qbase + j], s);
  }
}

// ---------------- triplet loss ----------------
__global__ __launch_bounds__(256) void loss_kernel(const float* __restrict__ dap,
                                                   const float* __restrict__ dan,
                                                   const float* __restrict__ comask,
                                                   float* __restrict__ out) {
  int t = threadIdx.x;
  float s = 0.f;
  for (int i = t; i < kB * kHW; i += 256) {
    float da = sqrtf(dap[i]);
    float db = sqrtf(dan[i]);
    float tr = fmaxf(da - db + 0.3f, 0.f);
    s += comask[i] * tr;
  }
  for (int off = 32; off; off >>= 1) s += __shfl_xor(s, off);
  __shared__ float sh[4];
  if ((t & 63) == 0) sh[t >> 6] = s;
  __syncthreads();
  if (t == 0)
    out[(size_t)kB * kC * kHW] = (sh[0] + sh[1] + sh[2] + sh[3]) * (1.f / (float)(kB * kHW));
}

extern "C" void kernel_launch(void* const* d_in, const int* in_sizes, int n_in,
                              void* d_out, int out_size, void* d_ws, size_t ws_size,
                              hipStream_t stream) {
  const float* fv = (const float*)d_in[0];
  const float* ft = (const float*)d_in[1];
  // d_in[2], d_in[3] (uncertain_v/t) unused, faithful to reference
  const float* qw = (const float*)d_in[4];
  const float* qb = (const float*)d_in[5];
  const float* kw = (const float*)d_in[6];
  const float* kb = (const float*)d_in[7];
  const int* pos_idx = (const int*)d_in[8];
  const int* neg_idx = (const int*)d_in[9];
  float* out = (float*)d_out;

  // workspace layout (floats); total 24,293,376 floats = 97.2 MB
  float* ws   = (float*)d_ws;
  float* fq   = ws;                                   // 64*512*288
  float* fk   = fq + (size_t)kB * kCQ * kHW;          // 64*512*288
  float* pr   = fk + (size_t)kB * kCQ * kHW;          // 64*288*288 (reused pos then neg)
  float* maskb   = pr + (size_t)kB * kHW * kHW;       // 64*288
  float* qinv    = maskb + kB * kHW;
  float* kinv    = qinv + kB * kHW;
  float* comaskb = kinv + kB * kHW;
  float* dap     = comaskb + kB * kHW;
  float* dan     = dap + kB * kHW;
  if (ws_size < (size_t)(24293376) * sizeof(float)) return;  // loud failure > OOB corruption

  zero_kernel<<<dim3((2 * kB * kHW + 255) / 256), 256, 0, stream>>>(dap, 2 * kB * kHW);
  mask_kernel<<<dim3(kB), 320, 0, stream>>>(fv, ft, maskb);
  conv_kernel<<<dim3(32, 32), 320, 0, stream>>>(fv, ft, qw, qb, fq);
  conv_kernel<<<dim3(32, 32), 320, 0, stream>>>(fv, ft, kw, kb, fk);
  norminv_kernel<<<dim3(kB, 2), 320, 0, stream>>>(fq, fk, qinv, kinv);

  // positive branch
  sim_kernel<<<dim3(9, kB), 320, 0, stream>>>(fq, fk, qinv, kinv, pos_idx, pr);
  softmax_kernel<<<dim3(kB * kHW), 320, 0, stream>>>(pr);
  comask_kernel<<<dim3(kB), 320, 0, stream>>>(pr, maskb, pos_idx, comaskb);
  warp_kernel<<<dim3(5, 32, kB), 256, 0, stream>>>(fv, ft, pr, maskb, pos_idx, out, dap, 1);

  // negative branch (reuses pr buffer)
  sim_kernel<<<dim3(9, kB), 320, 0, stream>>>(fq, fk, qinv, kinv, neg_idx, pr);
  softmax_kernel<<<dim3(kB * kHW), 320, 0, stream>>>(pr);
  warp_kernel<<<dim3(5, 32, kB), 256, 0, stream>>>(fv, ft, pr, maskb, neg_idx, out, dan, 0);

  loss_kernel<<<dim3(1), 256, 0, stream>>>(dap, dan, comaskb, out);
}

// Round 2
// 2440.131 us; speedup vs baseline: 7.9535x; 7.9535x over previous
//
#include <hip/hip_runtime.h>
#include <cstdint>
#include <cstddef>

// CMAlign forward. R2: bf16 MFMA implicit-GEMM conv (16x16x32), rest fp32.
// Shapes: B=64, C=2048, Cq=512, H=24, W=12, HW=288.

namespace {
constexpr int kB    = 64;
constexpr int kHalf = 32;
constexpr int kC    = 2048;
constexpr int kCQ   = 512;
constexpr int kH    = 24;
constexpr int kW    = 12;
constexpr int kHW   = 288;
constexpr float kTemp = 50.0f;
}

typedef __attribute__((ext_vector_type(8))) __bf16 bf16x8;
typedef __attribute__((ext_vector_type(4))) float f32x4;
typedef __attribute__((ext_vector_type(8))) unsigned short ushort8;

__device__ __forceinline__ const float* feat_base(const float* fv, const float* ft, int b) {
  return (b < kHalf) ? (fv + (size_t)b * kC * kHW)
                     : (ft + (size_t)(b - kHalf) * kC * kHW);
}

__device__ __forceinline__ unsigned short f2bf(float f) {
  union { float f; unsigned u; } c; c.f = f;
  unsigned u = c.u;
  unsigned r = (u + 0x7FFFu + ((u >> 16) & 1u)) >> 16;  // RNE
  return (unsigned short)r;
}

__device__ __forceinline__ void gload_lds16(const void* g, void* l) {
  __builtin_amdgcn_global_load_lds(
      (const __attribute__((address_space(1))) unsigned int*)g,
      (__attribute__((address_space(3))) unsigned int*)l, 16, 0, 0);
}

__global__ void zero_kernel(float* __restrict__ p, int n) {
  int i = blockIdx.x * 256 + threadIdx.x;
  if (i < n) p[i] = 0.f;
}

// ---------------- weight prep: w[oc][ic][3][3] fp32 -> wt[tap][oc][ic] bf16 ----------------
__global__ __launch_bounds__(256) void prep_w_kernel(const float* __restrict__ qw,
                                                     const float* __restrict__ kw,
                                                     unsigned short* __restrict__ wtq,
                                                     unsigned short* __restrict__ wtk) {
  int oc = blockIdx.x;
  int z  = blockIdx.y;
  const float* w = (z ? kw : qw) + (size_t)oc * (kC * 9);
  unsigned short* wt = z ? wtk : wtq;
  __shared__ unsigned short lw[kC * 9];  // [ic][tap], 36864 B
  int t = threadIdx.x;
#pragma unroll
  for (int it = 0; it < 18; ++it) {
    int i4 = (it * 256 + t) * 4;
    float4 v = *(const float4*)(w + i4);
    lw[i4 + 0] = f2bf(v.x);
    lw[i4 + 1] = f2bf(v.y);
    lw[i4 + 2] = f2bf(v.z);
    lw[i4 + 3] = f2bf(v.w);
  }
  __syncthreads();
  for (int item = t; item < 9 * 256; item += 256) {
    int tap = item >> 8;
    int ic  = (item & 255) * 8;
    ushort8 pk;
#pragma unroll
    for (int j = 0; j < 8; ++j) pk[j] = lw[(ic + j) * 9 + tap];
    *(ushort8*)(wt + ((size_t)(tap * kCQ + oc)) * kC + ic) = pk;
  }
}

// ---------------- MFMA conv: implicit GEMM, tile M=128(oc) x N=288(pos), K=2048x9 ----------------
// grid (4 Mtiles, 64 b), 512 threads (8 waves as 4M x 2N).
__global__ __launch_bounds__(512) void conv_mfma_kernel(const unsigned short* __restrict__ wt,
                                                        const float* __restrict__ bias,
                                                        const float* __restrict__ fv,
                                                        const float* __restrict__ ft,
                                                        float* __restrict__ outp) {
  __shared__ unsigned short Ws[9 * 128 * 32];  // [tap][oc][4 kg][8 ic] 73728 B
  __shared__ unsigned short Xs[364 * 32];      // [hp=26x14][4 kg][8 ic] 23296 B
  int t    = threadIdx.x;
  int lane = t & 63;
  int wid  = t >> 6;
  int l15  = lane & 15, kg = lane >> 4;
  int wm   = wid >> 1, wn = wid & 1;
  int oc0  = blockIdx.x * 128;
  int b    = blockIdx.y;
  const float* fb = feat_base(fv, ft, b);

  // Ws staging descriptors: item = r*512 + t = (tap*128+oc)*4 + kgi
  int woff[9];
#pragma unroll
  for (int r = 0; r < 9; ++r) {
    int item = r * 512 + t;
    int kgi  = item & 3;
    int rest = item >> 2;
    int tap  = rest >> 7;
    int oc   = rest & 127;
    woff[r] = (tap * kCQ + oc0 + oc) * kC + kgi * 8;  // + ic0 per chunk
  }
  // Xs staging descriptors: item = i*512 + t (< 1456), item = hp*4 + kgi
  int  xoff[3];
  bool xvalid[3], xhas[3];
#pragma unroll
  for (int i = 0; i < 3; ++i) {
    int item = i * 512 + t;
    xhas[i] = item < 1456;
    int kgi = item & 3;
    int hp  = item >> 2;
    int hy = hp / 14, hx = hp - hy * 14;
    int y = hy - 1, x = hx - 1;
    bool v = (y >= 0 && y < kH && x >= 0 && x < kW) && xhas[i];
    xvalid[i] = v;
    xoff[i] = v ? (kgi * 8) * kHW + y * kW + x : 0;
  }

  // fragment LDS byte addresses
  int aAddr[2];
#pragma unroll
  for (int fm = 0; fm < 2; ++fm)
    aAddr[fm] = ((wm * 32 + fm * 16 + l15) * 32 + kg * 8) * 2;
  int bAddr[9];
#pragma unroll
  for (int fn = 0; fn < 9; ++fn) {
    int p = wn * 144 + fn * 16 + l15;
    int y = p / kW, x = p - y * kW;
    bAddr[fn] = (((y + 1) * 14 + (x + 1)) * 32 + kg * 8) * 2;
  }

  f32x4 acc[2][9];
#pragma unroll
  for (int fm = 0; fm < 2; ++fm)
#pragma unroll
    for (int fn = 0; fn < 9; ++fn) acc[fm][fn] = (f32x4){0.f, 0.f, 0.f, 0.f};

  char* WsB = (char*)Ws;
  char* XsB = (char*)Xs;
  int wavebase = t & ~63;

#pragma unroll 1
  for (int chunk = 0; chunk < 64; ++chunk) {
    int ic0 = chunk * 32;
    __syncthreads();
    // async weight staging (9 x 512 items x 16B)
#pragma unroll
    for (int r = 0; r < 9; ++r)
      gload_lds16(wt + (size_t)(woff[r] + ic0), WsB + (size_t)(r * 512 + wavebase) * 16);
    // reg-staged X (fp32 -> bf16, zero-padded halo)
#pragma unroll
    for (int i = 0; i < 3; ++i) {
      if (!xhas[i]) continue;
      ushort8 pk;
      if (xvalid[i]) {
        const float* s = fb + (size_t)ic0 * kHW + xoff[i];
#pragma unroll
        for (int j = 0; j < 8; ++j) pk[j] = f2bf(s[(size_t)j * kHW]);
      } else {
#pragma unroll
        for (int j = 0; j < 8; ++j) pk[j] = 0;
      }
      *(ushort8*)(XsB + (size_t)(i * 512 + t) * 16) = pk;
    }
    __syncthreads();
    // 9 taps x (2 A-frags x 9 B-frags) MFMAs
#pragma unroll
    for (int tap = 0; tap < 9; ++tap) {
      int dy = tap / 3 - 1, dx = tap % 3 - 1;
      int tx = (dy * 14 + dx) * 64;
      int tw = tap * 8192;
      bf16x8 a0 = *(const bf16x8*)(WsB + tw + aAddr[0]);
      bf16x8 a1 = *(const bf16x8*)(WsB + tw + aAddr[1]);
#pragma unroll
      for (int fn = 0; fn < 9; ++fn) {
        bf16x8 bb = *(const bf16x8*)(XsB + tx + bAddr[fn]);
        acc[0][fn] = __builtin_amdgcn_mfma_f32_16x16x32_bf16(a0, bb, acc[0][fn], 0, 0, 0);
        acc[1][fn] = __builtin_amdgcn_mfma_f32_16x16x32_bf16(a1, bb, acc[1][fn], 0, 0, 0);
      }
    }
  }

  // epilogue: C row = (lane>>4)*4 + reg (oc), col = lane&15 (pos)
#pragma unroll
  for (int fm = 0; fm < 2; ++fm) {
#pragma unroll
    for (int fn = 0; fn < 9; ++fn) {
      int p = wn * 144 + fn * 16 + l15;
#pragma unroll
      for (int reg = 0; reg < 4; ++reg) {
        int oc = oc0 + wm * 32 + fm * 16 + kg * 4 + reg;
        outp[((size_t)b * kCQ + oc) * kHW + p] = acc[fm][fn][reg] + bias[oc];
      }
    }
  }
}

// ---------------- mask: per-sample min-max normalized channel L2 norm ----------------
__global__ __launch_bounds__(320) void mask_kernel(const float* __restrict__ fv,
                                                   const float* __restrict__ ft,
                                                   float* __restrict__ mask) {
  int b = blockIdx.x;
  int t = threadIdx.x;
  const float* fb = feat_base(fv, ft, b);
  float n = 0.f;
  if (t < kHW) {
    float s = 0.f;
    for (int c = 0; c < kC; ++c) { float v = fb[(size_t)c * kHW + t]; s += v * v; }
    n = sqrtf(s);
  }
  __shared__ float sh[320];
  sh[t] = (t < kHW) ? n : 3.4e38f;
  __syncthreads();
  float mn;
  {
    float m = 3.4e38f;
    if (t < 64) {
      for (int i = t; i < 320; i += 64) m = fminf(m, sh[i]);
      for (int off = 32; off; off >>= 1) m = fminf(m, __shfl_xor(m, off));
    }
    __syncthreads();
    if (t == 0) sh[0] = m;
    __syncthreads();
    mn = sh[0];
    __syncthreads();
  }
  sh[t] = (t < kHW) ? n : -3.4e38f;
  __syncthreads();
  float mx;
  {
    float m = -3.4e38f;
    if (t < 64) {
      for (int i = t; i < 320; i += 64) m = fmaxf(m, sh[i]);
      for (int off = 32; off; off >>= 1) m = fmaxf(m, __shfl_xor(m, off));
    }
    __syncthreads();
    if (t == 0) sh[0] = m;
    __syncthreads();
    mx = sh[0];
  }
  if (t < kHW) mask[b * kHW + t] = (n - mn) / ((mx - mn) + 1e-12f);
}

// ---------------- per-(b,pos) inverse L2 norm over projected channels ----------------
__global__ __launch_bounds__(320) void norminv_kernel(const float* __restrict__ fq,
                                                      const float* __restrict__ fk,
                                                      float* __restrict__ qinv,
                                                      float* __restrict__ kinv) {
  int b = blockIdx.x;
  int z = blockIdx.y;
  const float* src = z ? fk : fq;
  float* dst       = z ? kinv : qinv;
  int t = threadIdx.x;
  if (t >= kHW) return;
  const float* sb = src + (size_t)b * kCQ * kHW;
  float s = 0.f;
  for (int c = 0; c < kCQ; ++c) { float v = sb[(size_t)c * kHW + t]; s += v * v; }
  float n = sqrtf(s);
  dst[b * kHW + t] = 1.f / fmaxf(n, 1e-12f);
}

// ---------------- sim logits ----------------
__global__ __launch_bounds__(320) void sim_kernel(const float* __restrict__ fq,
                                                  const float* __restrict__ fk,
                                                  const float* __restrict__ qinv,
                                                  const float* __restrict__ kinv,
                                                  const int* __restrict__ idx,
                                                  float* __restrict__ logits) {
  int b  = blockIdx.y;
  int q0 = blockIdx.x * 32;
  int t  = threadIdx.x;
  if (t >= kHW) return;
  int tb = idx[b];
  const float* fqb = fq + (size_t)b * kCQ * kHW + q0;
  const float* fkb = fk + (size_t)tb * kCQ * kHW;
  float acc[32];
#pragma unroll
  for (int q = 0; q < 32; ++q) acc[q] = 0.f;
#pragma unroll 1
  for (int c = 0; c < kCQ; ++c) {
    float kv = fkb[(size_t)c * kHW + t];
#pragma unroll
    for (int q = 0; q < 32; ++q) acc[q] = fmaf(fqb[(size_t)c * kHW + q], kv, acc[q]);
  }
  float ks = kinv[tb * kHW + t];
#pragma unroll
  for (int q = 0; q < 32; ++q) {
    float lg = kTemp * qinv[b * kHW + q0 + q] * ks * acc[q];
    logits[((size_t)b * kHW + q0 + q) * kHW + t] = lg;
  }
}

// ---------------- row softmax over k (in place) ----------------
__global__ __launch_bounds__(320) void softmax_kernel(float* __restrict__ pr) {
  int row = blockIdx.x;
  int t   = threadIdx.x;
  float* rp = pr + (size_t)row * kHW;
  float v = (t < kHW) ? rp[t] : -3.4e38f;
  __shared__ float sh[5];
  int wv = t >> 6, l = t & 63;
  float m = v;
  for (int off = 32; off; off >>= 1) m = fmaxf(m, __shfl_xor(m, off));
  if (l == 0) sh[wv] = m;
  __syncthreads();
  if (t == 0) { float mm = sh[0]; for (int i = 1; i < 5; ++i) mm = fmaxf(mm, sh[i]); sh[0] = mm; }
  __syncthreads();
  m = sh[0];
  float e = (t < kHW) ? __expf(v - m) : 0.f;
  float s = e;
  for (int off = 32; off; off >>= 1) s += __shfl_xor(s, off);
  __syncthreads();
  if (l == 0) sh[wv] = s;
  __syncthreads();
  if (t == 0) { float ss = sh[0]; for (int i = 1; i < 5; ++i) ss += sh[i]; sh[0] = ss; }
  __syncthreads();
  s = sh[0];
  if (t < kHW) rp[t] = e / s;
}

// ---------------- comask ----------------
__global__ __launch_bounds__(320) void comask_kernel(const float* __restrict__ pr,
                                                     const float* __restrict__ mask,
                                                     const int* __restrict__ idx,
                                                     float* __restrict__ comask) {
  int b = blockIdx.x;
  int t = threadIdx.x;
  int tb = idx[b];
  __shared__ float mt[kHW];
  __shared__ float cm[kHW];
  __shared__ float red[320];
  if (t < kHW) mt[t] = mask[tb * kHW + t];
  __syncthreads();
  int wv = t >> 6, l = t & 63;
  for (int q = wv; q < kHW; q += 5) {
    const float* prow = pr + ((size_t)b * kHW + q) * kHW;
    float s = 0.f;
    for (int k = l; k < kHW; k += 64) s += prow[k] * mt[k];
    for (int off = 32; off; off >>= 1) s += __shfl_xor(s, off);
    if (l == 0) cm[q] = mask[b * kHW + q] * s;
  }
  __syncthreads();
  float v = (t < kHW) ? cm[t] : 0.f;
  red[t] = (t < kHW) ? v : 3.4e38f;
  __syncthreads();
  float mn;
  {
    float m = 3.4e38f;
    if (t < 64) {
      for (int i = t; i < 320; i += 64) m = fminf(m, red[i]);
      for (int off = 32; off; off >>= 1) m = fminf(m, __shfl_xor(m, off));
    }
    __syncthreads();
    if (t == 0) red[0] = m;
    __syncthreads();
    mn = red[0];
    __syncthreads();
  }
  red[t] = (t < kHW) ? v : -3.4e38f;
  __syncthreads();
  float mx;
  {
    float m = -3.4e38f;
    if (t < 64) {
      for (int i = t; i < 320; i += 64) m = fmaxf(m, red[i]);
      for (int off = 32; off; off >>= 1) m = fmaxf(m, __shfl_xor(m, off));
    }
    __syncthreads();
    if (t == 0) red[0] = m;
    __syncthreads();
    mx = red[0];
  }
  if (t < kHW) comask[b * kHW + t] = (v - mn) / ((mx - mn) + 1e-12f);
}

// ---------------- warp GEMM + recon + dist^2 ----------------
__global__ __launch_bounds__(256) void warp_kernel(const float* __restrict__ fv,
                                                   const float* __restrict__ ft,
                                                   const float* __restrict__ pr,
                                                   const float* __restrict__ maskp,
                                                   const int* __restrict__ idx,
                                                   float* __restrict__ outp,
                                                   float* __restrict__ dsq,
                                                   int write_out) {
  int b  = blockIdx.z;
  int c0 = blockIdx.y * 64;
  int q0 = blockIdx.x * 64;
  int t  = threadIdx.x;
  int tc = t & 15;
  int tq = t >> 4;
  int tb = idx[b];
  const float* tgt = feat_base(fv, ft, tb);
  const float* fb  = feat_base(fv, ft, b);
  __shared__ float As[16][68];
  __shared__ float Bs[16][68];
  float acc[4][4];
#pragma unroll
  for (int i = 0; i < 4; ++i)
#pragma unroll
    for (int j = 0; j < 4; ++j) acc[i][j] = 0.f;

#pragma unroll 1
  for (int k0 = 0; k0 < kHW; k0 += 16) {
    __syncthreads();
    for (int li = t; li < 1024; li += 256) {
      int cc = li >> 4, kk = li & 15;
      As[kk][cc] = tgt[(size_t)(c0 + cc) * kHW + k0 + kk];
    }
    for (int li = t; li < 1024; li += 256) {
      int qq = li >> 4, kk = li & 15;
      Bs[kk][qq] = (q0 + qq < kHW) ? pr[((size_t)b * kHW + q0 + qq) * kHW + k0 + kk] : 0.f;
    }
    __syncthreads();
#pragma unroll
    for (int kk = 0; kk < 16; ++kk) {
      const float4 a4 = *reinterpret_cast<const float4*>(&As[kk][tq * 4]);
      const float4 b4 = *reinterpret_cast<const float4*>(&Bs[kk][tc * 4]);
      float av[4] = {a4.x, a4.y, a4.z, a4.w};
      float bv[4] = {b4.x, b4.y, b4.z, b4.w};
#pragma unroll
      for (int i = 0; i < 4; ++i)
#pragma unroll
        for (int j = 0; j < 4; ++j) acc[i][j] = fmaf(av[i], bv[j], acc[i][j]);
    }
  }

  int qbase = q0 + tc * 4;
  float psum[4] = {0.f, 0.f, 0.f, 0.f};
  if (qbase < kHW) {
    float mj[4];
#pragma unroll
    for (int j = 0; j < 4; ++j) mj[j] = maskp[b * kHW + qbase + j];
#pragma unroll
    for (int i = 0; i < 4; ++i) {
      int c = c0 + tq * 4 + i;
      const float4 f4 = *reinterpret_cast<const float4*>(&fb[(size_t)c * kHW + qbase]);
      float fvv[4] = {f4.x, f4.y, f4.z, f4.w};
      float o[4];
#pragma unroll
      for (int j = 0; j < 4; ++j) {
        float Wv = acc[i][j];
        float d  = mj[j] * (fvv[j] - Wv) + 1e-6f;
        psum[j] += d * d;
        o[j] = mj[j] * Wv + (1.f - mj[j]) * fvv[j];
      }
      if (write_out) {
        float4 o4 = make_float4(o[0], o[1], o[2], o[3]);
        *reinterpret_cast<float4*>(&outp[((size_t)b * kC + c) * kHW + qbase]) = o4;
      }
    }
  }
#pragma unroll
  for (int j = 0; j < 4; ++j) {
    float s = psum[j];
    s += __shfl_xor(s, 16);
    s += __shfl_xor(s, 32);
    if (((t >> 4) & 3) == 0 && qbase < kHW)
      atomicAdd(&dsq[b * kHW + qbase + j], s);
  }
}

// ---------------- triplet loss ----------------
__global__ __launch_bounds__(256) void loss_kernel(const float* __restrict__ dap,
                                                   const float* __restrict__ dan,
                                                   const float* __restrict__ comask,
                                                   float* __restrict__ out) {
  int t = threadIdx.x;
  float s = 0.f;
  for (int i = t; i < kB * kHW; i += 256) {
    float da = sqrtf(dap[i]);
    float db = sqrtf(dan[i]);
    float tr = fmaxf(da - db + 0.3f, 0.f);
    s += comask[i] * tr;
  }
  for (int off = 32; off; off >>= 1) s += __shfl_xor(s, off);
  __shared__ float sh[4];
  if ((t & 63) == 0) sh[t >> 6] = s;
  __syncthreads();
  if (t == 0)
    out[(size_t)kB * kC * kHW] = (sh[0] + sh[1] + sh[2] + sh[3]) * (1.f / (float)(kB * kHW));
}

extern "C" void kernel_launch(void* const* d_in, const int* in_sizes, int n_in,
                              void* d_out, int out_size, void* d_ws, size_t ws_size,
                              hipStream_t stream) {
  const float* fv = (const float*)d_in[0];
  const float* ft = (const float*)d_in[1];
  const float* qw = (const float*)d_in[4];
  const float* qb = (const float*)d_in[5];
  const float* kw = (const float*)d_in[6];
  const float* kb = (const float*)d_in[7];
  const int* pos_idx = (const int*)d_in[8];
  const int* neg_idx = (const int*)d_in[9];
  float* out = (float*)d_out;

  // ws layout (bytes): fq 37.75M | fk 37.75M | wtq+wtk 37.75M (pr aliases here after convs) | small
  constexpr size_t kFQ = (size_t)kB * kCQ * kHW;          // 9,437,184 floats
  float* ws   = (float*)d_ws;
  float* fq   = ws;
  float* fk   = fq + kFQ;
  unsigned short* wtq = (unsigned short*)(fk + kFQ);      // 9 * 512 * 2048 u16
  unsigned short* wtk = wtq + (size_t)9 * kCQ * kC;
  float* pr   = (float*)wtq;                              // alias: 21.2MB < 37.75MB, live after convs
  float* maskb   = (float*)(wtk + (size_t)9 * kCQ * kC);
  float* qinv    = maskb + kB * kHW;
  float* kinv    = qinv + kB * kHW;
  float* comaskb = kinv + kB * kHW;
  float* dap     = comaskb + kB * kHW;
  float* dan     = dap + kB * kHW;
  if (ws_size < (size_t)113688576) return;  // loud failure > OOB corruption

  zero_kernel<<<dim3((2 * kB * kHW + 255) / 256), 256, 0, stream>>>(dap, 2 * kB * kHW);
  mask_kernel<<<dim3(kB), 320, 0, stream>>>(fv, ft, maskb);
  prep_w_kernel<<<dim3(kCQ, 2), 256, 0, stream>>>(qw, kw, wtq, wtk);
  conv_mfma_kernel<<<dim3(4, kB), 512, 0, stream>>>(wtq, qb, fv, ft, fq);
  conv_mfma_kernel<<<dim3(4, kB), 512, 0, stream>>>(wtk, kb, fv, ft, fk);
  norminv_kernel<<<dim3(kB, 2), 320, 0, stream>>>(fq, fk, qinv, kinv);

  // positive branch (pr overwrites wt region — weights dead now)
  sim_kernel<<<dim3(9, kB), 320, 0, stream>>>(fq, fk, qinv, kinv, pos_idx, pr);
  softmax_kernel<<<dim3(kB * kHW), 320, 0, stream>>>(pr);
  comask_kernel<<<dim3(kB), 320, 0, stream>>>(pr, maskb, pos_idx, comaskb);
  warp_kernel<<<dim3(5, 32, kB), 256, 0, stream>>>(fv, ft, pr, maskb, pos_idx, out, dap, 1);

  // negative branch
  sim_kernel<<<dim3(9, kB), 320, 0, stream>>>(fq, fk, qinv, kinv, neg_idx, pr);
  softmax_kernel<<<dim3(kB * kHW), 320, 0, stream>>>(pr);
  warp_kernel<<<dim3(5, 32, kB), 256, 0, stream>>>(fv, ft, pr, maskb, neg_idx, out, dan, 0);

  loss_kernel<<<dim3(1), 256, 0, stream>>>(dap, dan, comaskb, out);
}

// Round 3
// 1903.670 us; speedup vs baseline: 10.1948x; 1.2818x over previous
//
#include <hip/hip_runtime.h>
#include <cstdint>
#include <cstddef>

// CMAlign forward. R3: bf16 MFMA conv + bf16 MFMA warp GEMM (tgt hi/lo split), rest fp32.
// Shapes: B=64, C=2048, Cq=512, H=24, W=12, HW=288.

namespace {
constexpr int kB    = 64;
constexpr int kHalf = 32;
constexpr int kC    = 2048;
constexpr int kCQ   = 512;
constexpr int kH    = 24;
constexpr int kW    = 12;
constexpr int kHW   = 288;
constexpr float kTemp = 50.0f;
}

typedef __attribute__((ext_vector_type(8))) __bf16 bf16x8;
typedef __attribute__((ext_vector_type(4))) float f32x4;
typedef __attribute__((ext_vector_type(8))) unsigned short ushort8;

__device__ __forceinline__ const float* feat_base(const float* fv, const float* ft, int b) {
  return (b < kHalf) ? (fv + (size_t)b * kC * kHW)
                     : (ft + (size_t)(b - kHalf) * kC * kHW);
}

__device__ __forceinline__ unsigned short f2bf(float f) {
  union { float f; unsigned u; } c; c.f = f;
  unsigned u = c.u;
  unsigned r = (u + 0x7FFFu + ((u >> 16) & 1u)) >> 16;  // RNE
  return (unsigned short)r;
}

__device__ __forceinline__ float bf2f(unsigned short h) {
  union { unsigned u; float f; } c; c.u = ((unsigned)h) << 16;
  return c.f;
}

__device__ __forceinline__ void gload_lds16(const void* g, void* l) {
  __builtin_amdgcn_global_load_lds(
      (const __attribute__((address_space(1))) unsigned int*)g,
      (__attribute__((address_space(3))) unsigned int*)l, 16, 0, 0);
}

__global__ void zero_kernel(float* __restrict__ p, int n) {
  int i = blockIdx.x * 256 + threadIdx.x;
  if (i < n) p[i] = 0.f;
}

// ---------------- weight prep: w[oc][ic][3][3] fp32 -> wt[tap][oc][ic] bf16 ----------------
__global__ __launch_bounds__(256) void prep_w_kernel(const float* __restrict__ qw,
                                                     const float* __restrict__ kw,
                                                     unsigned short* __restrict__ wtq,
                                                     unsigned short* __restrict__ wtk) {
  int oc = blockIdx.x;
  int z  = blockIdx.y;
  const float* w = (z ? kw : qw) + (size_t)oc * (kC * 9);
  unsigned short* wt = z ? wtk : wtq;
  __shared__ unsigned short lw[kC * 9];
  int t = threadIdx.x;
#pragma unroll
  for (int it = 0; it < 18; ++it) {
    int i4 = (it * 256 + t) * 4;
    float4 v = *(const float4*)(w + i4);
    lw[i4 + 0] = f2bf(v.x);
    lw[i4 + 1] = f2bf(v.y);
    lw[i4 + 2] = f2bf(v.z);
    lw[i4 + 3] = f2bf(v.w);
  }
  __syncthreads();
  for (int item = t; item < 9 * 256; item += 256) {
    int tap = item >> 8;
    int ic  = (item & 255) * 8;
    ushort8 pk;
#pragma unroll
    for (int j = 0; j < 8; ++j) pk[j] = lw[(ic + j) * 9 + tap];
    *(ushort8*)(wt + ((size_t)(tap * kCQ + oc)) * kC + ic) = pk;
  }
}

// ---------------- MFMA conv: implicit GEMM, tile M=128(oc) x N=288(pos), K=2048x9 ----------------
// grid: 256 blocks, XCD-clustered so each XCD's blocks share one weight tile.
__global__ __launch_bounds__(512) void conv_mfma_kernel(const unsigned short* __restrict__ wt,
                                                        const float* __restrict__ bias,
                                                        const float* __restrict__ fv,
                                                        const float* __restrict__ ft,
                                                        float* __restrict__ outp) {
  __shared__ unsigned short Ws[9 * 128 * 32];  // 73728 B
  __shared__ unsigned short Xs[364 * 32];      // 23296 B
  int t    = threadIdx.x;
  int lane = t & 63;
  int wid  = t >> 6;
  int l15  = lane & 15, kg = lane >> 4;
  int wm   = wid >> 1, wn = wid & 1;
  // XCD-clustered decode: xcd = n&7 -> tile = xcd>>1, b = (xcd&1)*32 + n>>3
  int n    = blockIdx.x;
  int xcd  = n & 7;
  int oc0  = (xcd >> 1) * 128;
  int b    = ((xcd & 1) << 5) + (n >> 3);
  const float* fb = feat_base(fv, ft, b);

  int woff[9];
#pragma unroll
  for (int r = 0; r < 9; ++r) {
    int item = r * 512 + t;
    int kgi  = item & 3;
    int rest = item >> 2;
    int tap  = rest >> 7;
    int oc   = rest & 127;
    woff[r] = (tap * kCQ + oc0 + oc) * kC + kgi * 8;
  }
  int  xoff[3];
  bool xvalid[3], xhas[3];
#pragma unroll
  for (int i = 0; i < 3; ++i) {
    int item = i * 512 + t;
    xhas[i] = item < 1456;
    int kgi = item & 3;
    int hp  = item >> 2;
    int hy = hp / 14, hx = hp - hy * 14;
    int y = hy - 1, x = hx - 1;
    bool v = (y >= 0 && y < kH && x >= 0 && x < kW) && xhas[i];
    xvalid[i] = v;
    xoff[i] = v ? (kgi * 8) * kHW + y * kW + x : 0;
  }

  int aAddr[2];
#pragma unroll
  for (int fm = 0; fm < 2; ++fm)
    aAddr[fm] = ((wm * 32 + fm * 16 + l15) * 32 + kg * 8) * 2;
  int bAddr[9];
#pragma unroll
  for (int fn = 0; fn < 9; ++fn) {
    int p = wn * 144 + fn * 16 + l15;
    int y = p / kW, x = p - y * kW;
    bAddr[fn] = (((y + 1) * 14 + (x + 1)) * 32 + kg * 8) * 2;
  }

  f32x4 acc[2][9];
#pragma unroll
  for (int fm = 0; fm < 2; ++fm)
#pragma unroll
    for (int fn = 0; fn < 9; ++fn) acc[fm][fn] = (f32x4){0.f, 0.f, 0.f, 0.f};

  char* WsB = (char*)Ws;
  char* XsB = (char*)Xs;
  int wavebase = t & ~63;

#pragma unroll 1
  for (int chunk = 0; chunk < 64; ++chunk) {
    int ic0 = chunk * 32;
    __syncthreads();
#pragma unroll
    for (int r = 0; r < 9; ++r)
      gload_lds16(wt + (size_t)(woff[r] + ic0), WsB + (size_t)(r * 512 + wavebase) * 16);
#pragma unroll
    for (int i = 0; i < 3; ++i) {
      if (!xhas[i]) continue;
      ushort8 pk;
      if (xvalid[i]) {
        const float* s = fb + (size_t)ic0 * kHW + xoff[i];
#pragma unroll
        for (int j = 0; j < 8; ++j) pk[j] = f2bf(s[(size_t)j * kHW]);
      } else {
#pragma unroll
        for (int j = 0; j < 8; ++j) pk[j] = 0;
      }
      *(ushort8*)(XsB + (size_t)(i * 512 + t) * 16) = pk;
    }
    __syncthreads();
#pragma unroll
    for (int tap = 0; tap < 9; ++tap) {
      int dy = tap / 3 - 1, dx = tap % 3 - 1;
      int tx = (dy * 14 + dx) * 64;
      int tw = tap * 8192;
      bf16x8 a0 = *(const bf16x8*)(WsB + tw + aAddr[0]);
      bf16x8 a1 = *(const bf16x8*)(WsB + tw + aAddr[1]);
#pragma unroll
      for (int fn = 0; fn < 9; ++fn) {
        bf16x8 bb = *(const bf16x8*)(XsB + tx + bAddr[fn]);
        acc[0][fn] = __builtin_amdgcn_mfma_f32_16x16x32_bf16(a0, bb, acc[0][fn], 0, 0, 0);
        acc[1][fn] = __builtin_amdgcn_mfma_f32_16x16x32_bf16(a1, bb, acc[1][fn], 0, 0, 0);
      }
    }
  }

#pragma unroll
  for (int fm = 0; fm < 2; ++fm) {
#pragma unroll
    for (int fn = 0; fn < 9; ++fn) {
      int p = wn * 144 + fn * 16 + l15;
#pragma unroll
      for (int reg = 0; reg < 4; ++reg) {
        int oc = oc0 + wm * 32 + fm * 16 + kg * 4 + reg;
        outp[((size_t)b * kCQ + oc) * kHW + p] = acc[fm][fn][reg] + bias[oc];
      }
    }
  }
}

// ---------------- warp GEMM via MFMA: W[c,q] = sum_k tgt[c,k]*pr[q,k] + recon + dist^2 ----------------
// tgt split hi/lo bf16 (fp32-accurate), pr single bf16. Tile M=128 c, N=288 q (full), K=288.
__global__ __launch_bounds__(512) void warp_mfma_kernel(const float* __restrict__ fv,
                                                        const float* __restrict__ ft,
                                                        const unsigned short* __restrict__ prb,
                                                        const float* __restrict__ maskp,
                                                        const int* __restrict__ idx,
                                                        float* __restrict__ outp,
                                                        float* __restrict__ dsq,
                                                        int write_out) {
  __shared__ unsigned short AsHi[128 * 32];  // 8192 B
  __shared__ unsigned short AsLo[128 * 32];  // 8192 B
  __shared__ unsigned short Bs[288 * 32];    // 18432 B
  int t    = threadIdx.x;
  int lane = t & 63;
  int wid  = t >> 6;
  int l15  = lane & 15, kg = lane >> 4;
  int wm   = wid >> 1, wn = wid & 1;
  int c0   = blockIdx.x * 128;
  int b    = blockIdx.y;
  int tb   = idx[b];
  const float* tgt = feat_base(fv, ft, tb);
  const float* fb  = feat_base(fv, ft, b);

  // A staging: thread t -> row ar (c), slot as (8 k each); slot swizzled by (r^(r>>2))&3
  int ar = t >> 2, as = t & 3;
  int aslot = as ^ ((ar ^ (ar >> 2)) & 3);
  unsigned short* aDstHi = AsHi + ar * 32 + aslot * 8;
  unsigned short* aDstLo = AsLo + ar * 32 + aslot * 8;

  // frag read addresses (elem index into As*/Bs)
  int aIdx[2];
#pragma unroll
  for (int fm = 0; fm < 2; ++fm) {
    int r = wm * 32 + fm * 16 + l15;
    aIdx[fm] = r * 32 + (kg ^ ((r ^ (r >> 2)) & 3)) * 8;
  }
  int bIdx[9];
#pragma unroll
  for (int fn = 0; fn < 9; ++fn) {
    int q = wn * 144 + fn * 16 + l15;
    bIdx[fn] = q * 32 + (kg ^ ((q ^ (q >> 2)) & 3)) * 8;
  }

  f32x4 acc[2][9];
#pragma unroll
  for (int fm = 0; fm < 2; ++fm)
#pragma unroll
    for (int fn = 0; fn < 9; ++fn) acc[fm][fn] = (f32x4){0.f, 0.f, 0.f, 0.f};

#pragma unroll 1
  for (int chunk = 0; chunk < 9; ++chunk) {
    int k0 = chunk * 32;
    __syncthreads();
    // stage A (tgt fp32 -> hi/lo bf16)
    {
      const float* s = tgt + (size_t)(c0 + ar) * kHW + k0 + as * 8;
      float4 v0 = *(const float4*)(s);
      float4 v1 = *(const float4*)(s + 4);
      float xs[8] = {v0.x, v0.y, v0.z, v0.w, v1.x, v1.y, v1.z, v1.w};
      ushort8 hi, lo;
#pragma unroll
      for (int j = 0; j < 8; ++j) {
        unsigned short h = f2bf(xs[j]);
        hi[j] = h;
        lo[j] = f2bf(xs[j] - bf2f(h));
      }
      *(ushort8*)aDstHi = hi;
      *(ushort8*)aDstLo = lo;
    }
    // stage B (pr bf16, direct copy)
#pragma unroll
    for (int i = 0; i < 3; ++i) {
      int item = i * 512 + t;
      if (item < 1152) {
        int q = item >> 2, s = item & 3;
        ushort8 v = *(const ushort8*)(prb + ((size_t)b * kHW + q) * kHW + k0 + s * 8);
        *(ushort8*)(Bs + q * 32 + (s ^ ((q ^ (q >> 2)) & 3)) * 8) = v;
      }
    }
    __syncthreads();
    bf16x8 ah0 = *(const bf16x8*)(AsHi + aIdx[0]);
    bf16x8 al0 = *(const bf16x8*)(AsLo + aIdx[0]);
    bf16x8 ah1 = *(const bf16x8*)(AsHi + aIdx[1]);
    bf16x8 al1 = *(const bf16x8*)(AsLo + aIdx[1]);
#pragma unroll
    for (int fn = 0; fn < 9; ++fn) {
      bf16x8 bb = *(const bf16x8*)(Bs + bIdx[fn]);
      acc[0][fn] = __builtin_amdgcn_mfma_f32_16x16x32_bf16(ah0, bb, acc[0][fn], 0, 0, 0);
      acc[0][fn] = __builtin_amdgcn_mfma_f32_16x16x32_bf16(al0, bb, acc[0][fn], 0, 0, 0);
      acc[1][fn] = __builtin_amdgcn_mfma_f32_16x16x32_bf16(ah1, bb, acc[1][fn], 0, 0, 0);
      acc[1][fn] = __builtin_amdgcn_mfma_f32_16x16x32_bf16(al1, bb, acc[1][fn], 0, 0, 0);
    }
  }

  // epilogue: C row(c) = kg*4+reg (+fm*16+wm*32), col(q) = l15 (+fn*16+wn*144)
#pragma unroll
  for (int fn = 0; fn < 9; ++fn) {
    int q = wn * 144 + fn * 16 + l15;
    float mj = maskp[b * kHW + q];
    float psum = 0.f;
#pragma unroll
    for (int fm = 0; fm < 2; ++fm) {
#pragma unroll
      for (int reg = 0; reg < 4; ++reg) {
        int c = c0 + wm * 32 + fm * 16 + kg * 4 + reg;
        float fvv = fb[(size_t)c * kHW + q];
        float Wv  = acc[fm][fn][reg];
        float d   = mj * (fvv - Wv) + 1e-6f;
        psum      = fmaf(d, d, psum);
        if (write_out)
          outp[((size_t)b * kC + c) * kHW + q] = mj * Wv + (1.f - mj) * fvv;
      }
    }
    psum += __shfl_xor(psum, 16);
    psum += __shfl_xor(psum, 32);
    if (lane < 16) atomicAdd(&dsq[b * kHW + q], psum);
  }
}

// ---------------- mask: per-sample min-max normalized channel L2 norm ----------------
__global__ __launch_bounds__(320) void mask_kernel(const float* __restrict__ fv,
                                                   const float* __restrict__ ft,
                                                   float* __restrict__ mask) {
  int b = blockIdx.x;
  int t = threadIdx.x;
  const float* fb = feat_base(fv, ft, b);
  float n = 0.f;
  if (t < kHW) {
    float s = 0.f;
    for (int c = 0; c < kC; ++c) { float v = fb[(size_t)c * kHW + t]; s += v * v; }
    n = sqrtf(s);
  }
  __shared__ float sh[320];
  sh[t] = (t < kHW) ? n : 3.4e38f;
  __syncthreads();
  float mn;
  {
    float m = 3.4e38f;
    if (t < 64) {
      for (int i = t; i < 320; i += 64) m = fminf(m, sh[i]);
      for (int off = 32; off; off >>= 1) m = fminf(m, __shfl_xor(m, off));
    }
    __syncthreads();
    if (t == 0) sh[0] = m;
    __syncthreads();
    mn = sh[0];
    __syncthreads();
  }
  sh[t] = (t < kHW) ? n : -3.4e38f;
  __syncthreads();
  float mx;
  {
    float m = -3.4e38f;
    if (t < 64) {
      for (int i = t; i < 320; i += 64) m = fmaxf(m, sh[i]);
      for (int off = 32; off; off >>= 1) m = fmaxf(m, __shfl_xor(m, off));
    }
    __syncthreads();
    if (t == 0) sh[0] = m;
    __syncthreads();
    mx = sh[0];
  }
  if (t < kHW) mask[b * kHW + t] = (n - mn) / ((mx - mn) + 1e-12f);
}

// ---------------- per-(b,pos) inverse L2 norm over projected channels ----------------
__global__ __launch_bounds__(320) void norminv_kernel(const float* __restrict__ fq,
                                                      const float* __restrict__ fk,
                                                      float* __restrict__ qinv,
                                                      float* __restrict__ kinv) {
  int b = blockIdx.x;
  int z = blockIdx.y;
  const float* src = z ? fk : fq;
  float* dst       = z ? kinv : qinv;
  int t = threadIdx.x;
  if (t >= kHW) return;
  const float* sb = src + (size_t)b * kCQ * kHW;
  float s = 0.f;
  for (int c = 0; c < kCQ; ++c) { float v = sb[(size_t)c * kHW + t]; s += v * v; }
  float n = sqrtf(s);
  dst[b * kHW + t] = 1.f / fmaxf(n, 1e-12f);
}

// ---------------- sim logits ----------------
__global__ __launch_bounds__(320) void sim_kernel(const float* __restrict__ fq,
                                                  const float* __restrict__ fk,
                                                  const float* __restrict__ qinv,
                                                  const float* __restrict__ kinv,
                                                  const int* __restrict__ idx,
                                                  float* __restrict__ logits) {
  int b  = blockIdx.y;
  int q0 = blockIdx.x * 32;
  int t  = threadIdx.x;
  if (t >= kHW) return;
  int tb = idx[b];
  const float* fqb = fq + (size_t)b * kCQ * kHW + q0;
  const float* fkb = fk + (size_t)tb * kCQ * kHW;
  float acc[32];
#pragma unroll
  for (int q = 0; q < 32; ++q) acc[q] = 0.f;
#pragma unroll 1
  for (int c = 0; c < kCQ; ++c) {
    float kv = fkb[(size_t)c * kHW + t];
#pragma unroll
    for (int q = 0; q < 32; ++q) acc[q] = fmaf(fqb[(size_t)c * kHW + q], kv, acc[q]);
  }
  float ks = kinv[tb * kHW + t];
#pragma unroll
  for (int q = 0; q < 32; ++q) {
    float lg = kTemp * qinv[b * kHW + q0 + q] * ks * acc[q];
    logits[((size_t)b * kHW + q0 + q) * kHW + t] = lg;
  }
}

// ---------------- row softmax over k; fp32 out optional, bf16 out always ----------------
__global__ __launch_bounds__(320) void softmax_kernel(float* __restrict__ pr,
                                                      unsigned short* __restrict__ prb,
                                                      int write_fp32) {
  int row = blockIdx.x;
  int t   = threadIdx.x;
  float* rp = pr + (size_t)row * kHW;
  float v = (t < kHW) ? rp[t] : -3.4e38f;
  __shared__ float sh[5];
  int wv = t >> 6, l = t & 63;
  float m = v;
  for (int off = 32; off; off >>= 1) m = fmaxf(m, __shfl_xor(m, off));
  if (l == 0) sh[wv] = m;
  __syncthreads();
  if (t == 0) { float mm = sh[0]; for (int i = 1; i < 5; ++i) mm = fmaxf(mm, sh[i]); sh[0] = mm; }
  __syncthreads();
  m = sh[0];
  float e = (t < kHW) ? __expf(v - m) : 0.f;
  float s = e;
  for (int off = 32; off; off >>= 1) s += __shfl_xor(s, off);
  __syncthreads();
  if (l == 0) sh[wv] = s;
  __syncthreads();
  if (t == 0) { float ss = sh[0]; for (int i = 1; i < 5; ++i) ss += sh[i]; sh[0] = ss; }
  __syncthreads();
  s = sh[0];
  if (t < kHW) {
    float p = e / s;
    if (write_fp32) rp[t] = p;
    prb[(size_t)row * kHW + t] = f2bf(p);
  }
}

// ---------------- comask ----------------
__global__ __launch_bounds__(320) void comask_kernel(const float* __restrict__ pr,
                                                     const float* __restrict__ mask,
                                                     const int* __restrict__ idx,
                                                     float* __restrict__ comask) {
  int b = blockIdx.x;
  int t = threadIdx.x;
  int tb = idx[b];
  __shared__ float mt[kHW];
  __shared__ float cm[kHW];
  __shared__ float red[320];
  if (t < kHW) mt[t] = mask[tb * kHW + t];
  __syncthreads();
  int wv = t >> 6, l = t & 63;
  for (int q = wv; q < kHW; q += 5) {
    const float* prow = pr + ((size_t)b * kHW + q) * kHW;
    float s = 0.f;
    for (int k = l; k < kHW; k += 64) s += prow[k] * mt[k];
    for (int off = 32; off; off >>= 1) s += __shfl_xor(s, off);
    if (l == 0) cm[q] = mask[b * kHW + q] * s;
  }
  __syncthreads();
  float v = (t < kHW) ? cm[t] : 0.f;
  red[t] = (t < kHW) ? v : 3.4e38f;
  __syncthreads();
  float mn;
  {
    float m = 3.4e38f;
    if (t < 64) {
      for (int i = t; i < 320; i += 64) m = fminf(m, red[i]);
      for (int off = 32; off; off >>= 1) m = fminf(m, __shfl_xor(m, off));
    }
    __syncthreads();
    if (t == 0) red[0] = m;
    __syncthreads();
    mn = red[0];
    __syncthreads();
  }
  red[t] = (t < kHW) ? v : -3.4e38f;
  __syncthreads();
  float mx;
  {
    float m = -3.4e38f;
    if (t < 64) {
      for (int i = t; i < 320; i += 64) m = fmaxf(m, red[i]);
      for (int off = 32; off; off >>= 1) m = fmaxf(m, __shfl_xor(m, off));
    }
    __syncthreads();
    if (t == 0) red[0] = m;
    __syncthreads();
    mx = red[0];
  }
  if (t < kHW) comask[b * kHW + t] = (v - mn) / ((mx - mn) + 1e-12f);
}

// ---------------- triplet loss ----------------
__global__ __launch_bounds__(256) void loss_kernel(const float* __restrict__ dap,
                                                   const float* __restrict__ dan,
                                                   const float* __restrict__ comask,
                                                   float* __restrict__ out) {
  int t = threadIdx.x;
  float s = 0.f;
  for (int i = t; i < kB * kHW; i += 256) {
    float da = sqrtf(dap[i]);
    float db = sqrtf(dan[i]);
    float tr = fmaxf(da - db + 0.3f, 0.f);
    s += comask[i] * tr;
  }
  for (int off = 32; off; off >>= 1) s += __shfl_xor(s, off);
  __shared__ float sh[4];
  if ((t & 63) == 0) sh[t >> 6] = s;
  __syncthreads();
  if (t == 0)
    out[(size_t)kB * kC * kHW] = (sh[0] + sh[1] + sh[2] + sh[3]) * (1.f / (float)(kB * kHW));
}

extern "C" void kernel_launch(void* const* d_in, const int* in_sizes, int n_in,
                              void* d_out, int out_size, void* d_ws, size_t ws_size,
                              hipStream_t stream) {
  const float* fv = (const float*)d_in[0];
  const float* ft = (const float*)d_in[1];
  const float* qw = (const float*)d_in[4];
  const float* qb = (const float*)d_in[5];
  const float* kw = (const float*)d_in[6];
  const float* kb = (const float*)d_in[7];
  const int* pos_idx = (const int*)d_in[8];
  const int* neg_idx = (const int*)d_in[9];
  float* out = (float*)d_out;

  // ws layout: fq 37.75M | fk 37.75M | region3 37.75M = {wtq|wtk} then {pr fp32 21.2M | prb bf16 10.6M} | small
  constexpr size_t kFQ = (size_t)kB * kCQ * kHW;
  float* ws   = (float*)d_ws;
  float* fq   = ws;
  float* fk   = fq + kFQ;
  unsigned short* wtq = (unsigned short*)(fk + kFQ);
  unsigned short* wtk = wtq + (size_t)9 * kCQ * kC;
  float* pr   = (float*)wtq;                               // alias, live after convs
  unsigned short* prb = (unsigned short*)(pr + (size_t)kB * kHW * kHW);
  float* maskb   = (float*)(wtk + (size_t)9 * kCQ * kC);
  float* qinv    = maskb + kB * kHW;
  float* kinv    = qinv + kB * kHW;
  float* comaskb = kinv + kB * kHW;
  float* dap     = comaskb + kB * kHW;
  float* dan     = dap + kB * kHW;
  if (ws_size < (size_t)113688576) return;

  zero_kernel<<<dim3((2 * kB * kHW + 255) / 256), 256, 0, stream>>>(dap, 2 * kB * kHW);
  mask_kernel<<<dim3(kB), 320, 0, stream>>>(fv, ft, maskb);
  prep_w_kernel<<<dim3(kCQ, 2), 256, 0, stream>>>(qw, kw, wtq, wtk);
  conv_mfma_kernel<<<dim3(256), 512, 0, stream>>>(wtq, qb, fv, ft, fq);
  conv_mfma_kernel<<<dim3(256), 512, 0, stream>>>(wtk, kb, fv, ft, fk);
  norminv_kernel<<<dim3(kB, 2), 320, 0, stream>>>(fq, fk, qinv, kinv);

  // positive branch (pr/prb overwrite wt region — weights dead now)
  sim_kernel<<<dim3(9, kB), 320, 0, stream>>>(fq, fk, qinv, kinv, pos_idx, pr);
  softmax_kernel<<<dim3(kB * kHW), 320, 0, stream>>>(pr, prb, 1);
  comask_kernel<<<dim3(kB), 320, 0, stream>>>(pr, maskb, pos_idx, comaskb);
  warp_mfma_kernel<<<dim3(16, kB), 512, 0, stream>>>(fv, ft, prb, maskb, pos_idx, out, dap, 1);

  // negative branch
  sim_kernel<<<dim3(9, kB), 320, 0, stream>>>(fq, fk, qinv, kinv, neg_idx, pr);
  softmax_kernel<<<dim3(kB * kHW), 320, 0, stream>>>(pr, prb, 0);
  warp_mfma_kernel<<<dim3(16, kB), 512, 0, stream>>>(fv, ft, prb, maskb, neg_idx, out, dan, 0);

  loss_kernel<<<dim3(1), 256, 0, stream>>>(dap, dan, comaskb, out);
}

// Round 4
// 1858.351 us; speedup vs baseline: 10.4434x; 1.0244x over previous
//
#include <hip/hip_runtime.h>
#include <cstdint>
#include <cstddef>

// CMAlign forward. R4: conv LDS layouts k-major (conflict-free), 2Mx4N wave tile,
// X prefetch-to-regs. bf16 MFMA conv + bf16 MFMA warp GEMM (tgt hi/lo split), rest fp32.
// Shapes: B=64, C=2048, Cq=512, H=24, W=12, HW=288.

namespace {
constexpr int kB    = 64;
constexpr int kHalf = 32;
constexpr int kC    = 2048;
constexpr int kCQ   = 512;
constexpr int kH    = 24;
constexpr int kW    = 12;
constexpr int kHW   = 288;
constexpr float kTemp = 50.0f;
}

typedef __attribute__((ext_vector_type(8))) __bf16 bf16x8;
typedef __attribute__((ext_vector_type(4))) float f32x4;
typedef __attribute__((ext_vector_type(8))) unsigned short ushort8;

__device__ __forceinline__ const float* feat_base(const float* fv, const float* ft, int b) {
  return (b < kHalf) ? (fv + (size_t)b * kC * kHW)
                     : (ft + (size_t)(b - kHalf) * kC * kHW);
}

__device__ __forceinline__ unsigned short f2bf(float f) {
  union { float f; unsigned u; } c; c.f = f;
  unsigned u = c.u;
  unsigned r = (u + 0x7FFFu + ((u >> 16) & 1u)) >> 16;  // RNE
  return (unsigned short)r;
}

__device__ __forceinline__ float bf2f(unsigned short h) {
  union { unsigned u; float f; } c; c.u = ((unsigned)h) << 16;
  return c.f;
}

__device__ __forceinline__ void gload_lds16(const void* g, void* l) {
  __builtin_amdgcn_global_load_lds(
      (const __attribute__((address_space(1))) unsigned int*)g,
      (__attribute__((address_space(3))) unsigned int*)l, 16, 0, 0);
}

__global__ void zero_kernel(float* __restrict__ p, int n) {
  int i = blockIdx.x * 256 + threadIdx.x;
  if (i < n) p[i] = 0.f;
}

// ---------------- weight prep: w[oc][ic][3][3] fp32 -> wt[tap][oc][ic] bf16 ----------------
__global__ __launch_bounds__(256) void prep_w_kernel(const float* __restrict__ qw,
                                                     const float* __restrict__ kw,
                                                     unsigned short* __restrict__ wtq,
                                                     unsigned short* __restrict__ wtk) {
  int oc = blockIdx.x;
  int z  = blockIdx.y;
  const float* w = (z ? kw : qw) + (size_t)oc * (kC * 9);
  unsigned short* wt = z ? wtk : wtq;
  __shared__ unsigned short lw[kC * 9];
  int t = threadIdx.x;
#pragma unroll
  for (int it = 0; it < 18; ++it) {
    int i4 = (it * 256 + t) * 4;
    float4 v = *(const float4*)(w + i4);
    lw[i4 + 0] = f2bf(v.x);
    lw[i4 + 1] = f2bf(v.y);
    lw[i4 + 2] = f2bf(v.z);
    lw[i4 + 3] = f2bf(v.w);
  }
  __syncthreads();
  for (int item = t; item < 9 * 256; item += 256) {
    int tap = item >> 8;
    int ic  = (item & 255) * 8;
    ushort8 pk;
#pragma unroll
    for (int j = 0; j < 8; ++j) pk[j] = lw[(ic + j) * 9 + tap];
    *(ushort8*)(wt + ((size_t)(tap * kCQ + oc)) * kC + ic) = pk;
  }
}

// ---------------- MFMA conv: implicit GEMM, tile M=128(oc) x N=288(pos), K=2048x9 ----------------
// k-major LDS layouts: Ws[tap][kg][oc][8ic], Xs[kg][hp][8ic] -> conflict-free ds_read_b128.
// 8 waves as 2M x 4N (fn frags 5/5/4/4, interleaved across SIMDs). X prefetched to regs.
__global__ __launch_bounds__(512, 2) void conv_mfma_kernel(const unsigned short* __restrict__ wt,
                                                           const float* __restrict__ bias,
                                                           const float* __restrict__ fv,
                                                           const float* __restrict__ ft,
                                                           float* __restrict__ outp) {
  __shared__ unsigned short Ws[9 * 4 * 128 * 8];  // [tap][kg][oc][8ic] 73728 B
  __shared__ unsigned short Xs[4 * 364 * 8];      // [kg][hp][8ic]     23296 B
  int t    = threadIdx.x;
  int lane = t & 63;
  int wid  = t >> 6;
  int l15  = lane & 15, kg = lane >> 4;
  int wm   = wid & 1, wn = wid >> 1;  // 2M x 4N; wm on bit0 so each SIMD gets one 5-frag + one 4-frag wave
  // XCD-clustered decode: xcd = n&7 -> tile = xcd>>1, b = (xcd&1)*32 + n>>3
  int n    = blockIdx.x;
  int xcd  = n & 7;
  int oc0  = (xcd >> 1) * 128;
  int b    = ((xcd & 1) << 5) + (n >> 3);
  const float* fb = feat_base(fv, ft, b);

  // Ws staging: LDS item = r*512 + t; item = (tap*4 + kg)*128 + oc (linear in k-major layout)
  int woff[9];
#pragma unroll
  for (int r = 0; r < 9; ++r) {
    int item = r * 512 + t;
    woff[r] = ((item >> 9) * kCQ + oc0 + (item & 127)) * kC + ((item >> 7) & 3) * 8;
  }
  // Xs staging: item = xkg*364 + hp (1456 items)
  int  xoff[3];
  bool xvalid[3], xhas[3];
#pragma unroll
  for (int i = 0; i < 3; ++i) {
    int item = i * 512 + t;
    xhas[i] = item < 1456;
    int xkg = item / 364;
    int hp  = item - xkg * 364;
    int hy = hp / 14, hx = hp - hy * 14;
    int y = hy - 1, x = hx - 1;
    bool v = (y >= 0 && y < kH && x >= 0 && x < kW) && xhas[i];
    xvalid[i] = v;
    xoff[i] = v ? (xkg * 8) * kHW + y * kW + x : 0;
  }

  // fragment read byte addresses
  int aAddr[4];
#pragma unroll
  for (int fm = 0; fm < 4; ++fm) {
    int r = wm * 64 + fm * 16 + l15;
    aAddr[fm] = (kg * 128 + r) * 16;  // + tap*8192 per tap
  }
  int nfn = (wn < 2) ? 5 : 4;
  int fnb = (wn < 2) ? wn * 5 : 10 + (wn - 2) * 4;
  int bAddr[5], pP[5];
#pragma unroll
  for (int fi = 0; fi < 5; ++fi) {
    int p = (fnb + fi) * 16 + l15;
    if (p > 287) p = 287;  // only hit for unused frags (fi >= nfn)
    pP[fi] = p;
    int y = p / kW, x = p - y * kW;
    bAddr[fi] = kg * 5824 + ((y + 1) * 14 + (x + 1)) * 16;  // + d*16 per tap
  }

  f32x4 acc[4][5];
#pragma unroll
  for (int fm = 0; fm < 4; ++fm)
#pragma unroll
    for (int fi = 0; fi < 5; ++fi) acc[fm][fi] = (f32x4){0.f, 0.f, 0.f, 0.f};

  float xr[3][8];
#pragma unroll
  for (int i = 0; i < 3; ++i)
#pragma unroll
    for (int j = 0; j < 8; ++j) xr[i][j] = 0.f;

  char* WsB = (char*)Ws;
  char* XsB = (char*)Xs;
  int wavebase = t & ~63;

  // prefetch chunk 0's X into regs
#pragma unroll
  for (int i = 0; i < 3; ++i)
    if (xvalid[i]) {
      const float* s = fb + xoff[i];
#pragma unroll
      for (int j = 0; j < 8; ++j) xr[i][j] = s[(size_t)j * kHW];
    }

#pragma unroll 1
  for (int chunk = 0; chunk < 64; ++chunk) {
    int ic0 = chunk * 32;
    __syncthreads();
    // async weight staging (linear LDS dest, per-lane global src)
#pragma unroll
    for (int r = 0; r < 9; ++r)
      gload_lds16(wt + (size_t)(woff[r] + ic0), WsB + (size_t)(r * 512 + wavebase) * 16);
    // X: cvt prefetched regs -> ds_write (k-major layout)
#pragma unroll
    for (int i = 0; i < 3; ++i) {
      if (!xhas[i]) continue;
      ushort8 pk;
#pragma unroll
      for (int j = 0; j < 8; ++j) pk[j] = f2bf(xr[i][j]);
      *(ushort8*)(XsB + (size_t)(i * 512 + t) * 16) = pk;
    }
    __syncthreads();
    // prefetch next chunk's X (flies during MFMA phase; next top-barrier drains it)
    if (chunk < 63) {
      int icn = ic0 + 32;
#pragma unroll
      for (int i = 0; i < 3; ++i)
        if (xvalid[i]) {
          const float* s = fb + (size_t)icn * kHW + xoff[i];
#pragma unroll
          for (int j = 0; j < 8; ++j) xr[i][j] = s[(size_t)j * kHW];
        }
    }
    // MFMA phase: 9 taps x (4 A-frags x nfn B-frags)
#pragma unroll
    for (int tap = 0; tap < 9; ++tap) {
      int d16 = ((tap / 3 - 1) * 14 + (tap % 3 - 1)) * 16;
      int tA  = tap * 8192;
      bf16x8 af[4];
#pragma unroll
      for (int fm = 0; fm < 4; ++fm) af[fm] = *(const bf16x8*)(WsB + tA + aAddr[fm]);
#pragma unroll
      for (int fi = 0; fi < 5; ++fi) {
        if (fi >= nfn) continue;  // wave-uniform
        bf16x8 bb = *(const bf16x8*)(XsB + bAddr[fi] + d16);
#pragma unroll
        for (int fm = 0; fm < 4; ++fm)
          acc[fm][fi] = __builtin_amdgcn_mfma_f32_16x16x32_bf16(af[fm], bb, acc[fm][fi], 0, 0, 0);
      }
    }
  }

  // epilogue: C row(oc) = kg*4+reg (+fm*16+wm*64), col(p) = l15 (+frag base)
#pragma unroll
  for (int fi = 0; fi < 5; ++fi) {
    if (fi >= nfn) continue;
    int p = pP[fi];
#pragma unroll
    for (int fm = 0; fm < 4; ++fm)
#pragma unroll
      for (int reg = 0; reg < 4; ++reg) {
        int oc = oc0 + wm * 64 + fm * 16 + kg * 4 + reg;
        outp[((size_t)b * kCQ + oc) * kHW + p] = acc[fm][fi][reg] + bias[oc];
      }
  }
}

// ---------------- warp GEMM via MFMA: W[c,q] = sum_k tgt[c,k]*pr[q,k] + recon + dist^2 ----------------
// tgt split hi/lo bf16 (fp32-accurate), pr single bf16. Tile M=128 c, N=288 q (full), K=288.
__global__ __launch_bounds__(512) void warp_mfma_kernel(const float* __restrict__ fv,
                                                        const float* __restrict__ ft,
                                                        const unsigned short* __restrict__ prb,
                                                        const float* __restrict__ maskp,
                                                        const int* __restrict__ idx,
                                                        float* __restrict__ outp,
                                                        float* __restrict__ dsq,
                                                        int write_out) {
  __shared__ unsigned short AsHi[128 * 32];  // 8192 B
  __shared__ unsigned short AsLo[128 * 32];  // 8192 B
  __shared__ unsigned short Bs[288 * 32];    // 18432 B
  int t    = threadIdx.x;
  int lane = t & 63;
  int wid  = t >> 6;
  int l15  = lane & 15, kg = lane >> 4;
  int wm   = wid >> 1, wn = wid & 1;
  int c0   = blockIdx.x * 128;
  int b    = blockIdx.y;
  int tb   = idx[b];
  const float* tgt = feat_base(fv, ft, tb);
  const float* fb  = feat_base(fv, ft, b);

  // A staging: thread t -> row ar (c), slot as (8 k each); slot swizzled by (r^(r>>2))&3
  int ar = t >> 2, as = t & 3;
  int aslot = as ^ ((ar ^ (ar >> 2)) & 3);
  unsigned short* aDstHi = AsHi + ar * 32 + aslot * 8;
  unsigned short* aDstLo = AsLo + ar * 32 + aslot * 8;

  int aIdx[2];
#pragma unroll
  for (int fm = 0; fm < 2; ++fm) {
    int r = wm * 32 + fm * 16 + l15;
    aIdx[fm] = r * 32 + (kg ^ ((r ^ (r >> 2)) & 3)) * 8;
  }
  int bIdx[9];
#pragma unroll
  for (int fn = 0; fn < 9; ++fn) {
    int q = wn * 144 + fn * 16 + l15;
    bIdx[fn] = q * 32 + (kg ^ ((q ^ (q >> 2)) & 3)) * 8;
  }

  f32x4 acc[2][9];
#pragma unroll
  for (int fm = 0; fm < 2; ++fm)
#pragma unroll
    for (int fn = 0; fn < 9; ++fn) acc[fm][fn] = (f32x4){0.f, 0.f, 0.f, 0.f};

#pragma unroll 1
  for (int chunk = 0; chunk < 9; ++chunk) {
    int k0 = chunk * 32;
    __syncthreads();
    {
      const float* s = tgt + (size_t)(c0 + ar) * kHW + k0 + as * 8;
      float4 v0 = *(const float4*)(s);
      float4 v1 = *(const float4*)(s + 4);
      float xs[8] = {v0.x, v0.y, v0.z, v0.w, v1.x, v1.y, v1.z, v1.w};
      ushort8 hi, lo;
#pragma unroll
      for (int j = 0; j < 8; ++j) {
        unsigned short h = f2bf(xs[j]);
        hi[j] = h;
        lo[j] = f2bf(xs[j] - bf2f(h));
      }
      *(ushort8*)aDstHi = hi;
      *(ushort8*)aDstLo = lo;
    }
#pragma unroll
    for (int i = 0; i < 3; ++i) {
      int item = i * 512 + t;
      if (item < 1152) {
        int q = item >> 2, s = item & 3;
        ushort8 v = *(const ushort8*)(prb + ((size_t)b * kHW + q) * kHW + k0 + s * 8);
        *(ushort8*)(Bs + q * 32 + (s ^ ((q ^ (q >> 2)) & 3)) * 8) = v;
      }
    }
    __syncthreads();
    bf16x8 ah0 = *(const bf16x8*)(AsHi + aIdx[0]);
    bf16x8 al0 = *(const bf16x8*)(AsLo + aIdx[0]);
    bf16x8 ah1 = *(const bf16x8*)(AsHi + aIdx[1]);
    bf16x8 al1 = *(const bf16x8*)(AsLo + aIdx[1]);
#pragma unroll
    for (int fn = 0; fn < 9; ++fn) {
      bf16x8 bb = *(const bf16x8*)(Bs + bIdx[fn]);
      acc[0][fn] = __builtin_amdgcn_mfma_f32_16x16x32_bf16(ah0, bb, acc[0][fn], 0, 0, 0);
      acc[0][fn] = __builtin_amdgcn_mfma_f32_16x16x32_bf16(al0, bb, acc[0][fn], 0, 0, 0);
      acc[1][fn] = __builtin_amdgcn_mfma_f32_16x16x32_bf16(ah1, bb, acc[1][fn], 0, 0, 0);
      acc[1][fn] = __builtin_amdgcn_mfma_f32_16x16x32_bf16(al1, bb, acc[1][fn], 0, 0, 0);
    }
  }

#pragma unroll
  for (int fn = 0; fn < 9; ++fn) {
    int q = wn * 144 + fn * 16 + l15;
    float mj = maskp[b * kHW + q];
    float psum = 0.f;
#pragma unroll
    for (int fm = 0; fm < 2; ++fm) {
#pragma unroll
      for (int reg = 0; reg < 4; ++reg) {
        int c = c0 + wm * 32 + fm * 16 + kg * 4 + reg;
        float fvv = fb[(size_t)c * kHW + q];
        float Wv  = acc[fm][fn][reg];
        float d   = mj * (fvv - Wv) + 1e-6f;
        psum      = fmaf(d, d, psum);
        if (write_out)
          outp[((size_t)b * kC + c) * kHW + q] = mj * Wv + (1.f - mj) * fvv;
      }
    }
    psum += __shfl_xor(psum, 16);
    psum += __shfl_xor(psum, 32);
    if (lane < 16) atomicAdd(&dsq[b * kHW + q], psum);
  }
}

// ---------------- mask: per-sample min-max normalized channel L2 norm ----------------
__global__ __launch_bounds__(320) void mask_kernel(const float* __restrict__ fv,
                                                   const float* __restrict__ ft,
                                                   float* __restrict__ mask) {
  int b = blockIdx.x;
  int t = threadIdx.x;
  const float* fb = feat_base(fv, ft, b);
  float n = 0.f;
  if (t < kHW) {
    float s = 0.f;
    for (int c = 0; c < kC; ++c) { float v = fb[(size_t)c * kHW + t]; s += v * v; }
    n = sqrtf(s);
  }
  __shared__ float sh[320];
  sh[t] = (t < kHW) ? n : 3.4e38f;
  __syncthreads();
  float mn;
  {
    float m = 3.4e38f;
    if (t < 64) {
      for (int i = t; i < 320; i += 64) m = fminf(m, sh[i]);
      for (int off = 32; off; off >>= 1) m = fminf(m, __shfl_xor(m, off));
    }
    __syncthreads();
    if (t == 0) sh[0] = m;
    __syncthreads();
    mn = sh[0];
    __syncthreads();
  }
  sh[t] = (t < kHW) ? n : -3.4e38f;
  __syncthreads();
  float mx;
  {
    float m = -3.4e38f;
    if (t < 64) {
      for (int i = t; i < 320; i += 64) m = fmaxf(m, sh[i]);
      for (int off = 32; off; off >>= 1) m = fmaxf(m, __shfl_xor(m, off));
    }
    __syncthreads();
    if (t == 0) sh[0] = m;
    __syncthreads();
    mx = sh[0];
  }
  if (t < kHW) mask[b * kHW + t] = (n - mn) / ((mx - mn) + 1e-12f);
}

// ---------------- per-(b,pos) inverse L2 norm over projected channels ----------------
__global__ __launch_bounds__(320) void norminv_kernel(const float* __restrict__ fq,
                                                      const float* __restrict__ fk,
                                                      float* __restrict__ qinv,
                                                      float* __restrict__ kinv) {
  int b = blockIdx.x;
  int z = blockIdx.y;
  const float* src = z ? fk : fq;
  float* dst       = z ? kinv : qinv;
  int t = threadIdx.x;
  if (t >= kHW) return;
  const float* sb = src + (size_t)b * kCQ * kHW;
  float s = 0.f;
  for (int c = 0; c < kCQ; ++c) { float v = sb[(size_t)c * kHW + t]; s += v * v; }
  float n = sqrtf(s);
  dst[b * kHW + t] = 1.f / fmaxf(n, 1e-12f);
}

// ---------------- sim logits ----------------
__global__ __launch_bounds__(320) void sim_kernel(const float* __restrict__ fq,
                                                  const float* __restrict__ fk,
                                                  const float* __restrict__ qinv,
                                                  const float* __restrict__ kinv,
                                                  const int* __restrict__ idx,
                                                  float* __restrict__ logits) {
  int b  = blockIdx.y;
  int q0 = blockIdx.x * 32;
  int t  = threadIdx.x;
  if (t >= kHW) return;
  int tb = idx[b];
  const float* fqb = fq + (size_t)b * kCQ * kHW + q0;
  const float* fkb = fk + (size_t)tb * kCQ * kHW;
  float acc[32];
#pragma unroll
  for (int q = 0; q < 32; ++q) acc[q] = 0.f;
#pragma unroll 1
  for (int c = 0; c < kCQ; ++c) {
    float kv = fkb[(size_t)c * kHW + t];
#pragma unroll
    for (int q = 0; q < 32; ++q) acc[q] = fmaf(fqb[(size_t)c * kHW + q], kv, acc[q]);
  }
  float ks = kinv[tb * kHW + t];
#pragma unroll
  for (int q = 0; q < 32; ++q) {
    float lg = kTemp * qinv[b * kHW + q0 + q] * ks * acc[q];
    logits[((size_t)b * kHW + q0 + q) * kHW + t] = lg;
  }
}

// ---------------- row softmax over k; fp32 out optional, bf16 out always ----------------
__global__ __launch_bounds__(320) void softmax_kernel(float* __restrict__ pr,
                                                      unsigned short* __restrict__ prb,
                                                      int write_fp32) {
  int row = blockIdx.x;
  int t   = threadIdx.x;
  float* rp = pr + (size_t)row * kHW;
  float v = (t < kHW) ? rp[t] : -3.4e38f;
  __shared__ float sh[5];
  int wv = t >> 6, l = t & 63;
  float m = v;
  for (int off = 32; off; off >>= 1) m = fmaxf(m, __shfl_xor(m, off));
  if (l == 0) sh[wv] = m;
  __syncthreads();
  if (t == 0) { float mm = sh[0]; for (int i = 1; i < 5; ++i) mm = fmaxf(mm, sh[i]); sh[0] = mm; }
  __syncthreads();
  m = sh[0];
  float e = (t < kHW) ? __expf(v - m) : 0.f;
  float s = e;
  for (int off = 32; off; off >>= 1) s += __shfl_xor(s, off);
  __syncthreads();
  if (l == 0) sh[wv] = s;
  __syncthreads();
  if (t == 0) { float ss = sh[0]; for (int i = 1; i < 5; ++i) ss += sh[i]; sh[0] = ss; }
  __syncthreads();
  s = sh[0];
  if (t < kHW) {
    float p = e / s;
    if (write_fp32) rp[t] = p;
    prb[(size_t)row * kHW + t] = f2bf(p);
  }
}

// ---------------- comask ----------------
__global__ __launch_bounds__(320) void comask_kernel(const float* __restrict__ pr,
                                                     const float* __restrict__ mask,
                                                     const int* __restrict__ idx,
                                                     float* __restrict__ comask) {
  int b = blockIdx.x;
  int t = threadIdx.x;
  int tb = idx[b];
  __shared__ float mt[kHW];
  __shared__ float cm[kHW];
  __shared__ float red[320];
  if (t < kHW) mt[t] = mask[tb * kHW + t];
  __syncthreads();
  int wv = t >> 6, l = t & 63;
  for (int q = wv; q < kHW; q += 5) {
    const float* prow = pr + ((size_t)b * kHW + q) * kHW;
    float s = 0.f;
    for (int k = l; k < kHW; k += 64) s += prow[k] * mt[k];
    for (int off = 32; off; off >>= 1) s += __shfl_xor(s, off);
    if (l == 0) cm[q] = mask[b * kHW + q] * s;
  }
  __syncthreads();
  float v = (t < kHW) ? cm[t] : 0.f;
  red[t] = (t < kHW) ? v : 3.4e38f;
  __syncthreads();
  float mn;
  {
    float m = 3.4e38f;
    if (t < 64) {
      for (int i = t; i < 320; i += 64) m = fminf(m, red[i]);
      for (int off = 32; off; off >>= 1) m = fminf(m, __shfl_xor(m, off));
    }
    __syncthreads();
    if (t == 0) red[0] = m;
    __syncthreads();
    mn = red[0];
    __syncthreads();
  }
  red[t] = (t < kHW) ? v : -3.4e38f;
  __syncthreads();
  float mx;
  {
    float m = -3.4e38f;
    if (t < 64) {
      for (int i = t; i < 320; i += 64) m = fmaxf(m, red[i]);
      for (int off = 32; off; off >>= 1) m = fmaxf(m, __shfl_xor(m, off));
    }
    __syncthreads();
    if (t == 0) red[0] = m;
    __syncthreads();
    mx = red[0];
  }
  if (t < kHW) comask[b * kHW + t] = (v - mn) / ((mx - mn) + 1e-12f);
}

// ---------------- triplet loss ----------------
__global__ __launch_bounds__(256) void loss_kernel(const float* __restrict__ dap,
                                                   const float* __restrict__ dan,
                                                   const float* __restrict__ comask,
                                                   float* __restrict__ out) {
  int t = threadIdx.x;
  float s = 0.f;
  for (int i = t; i < kB * kHW; i += 256) {
    float da = sqrtf(dap[i]);
    float db = sqrtf(dan[i]);
    float tr = fmaxf(da - db + 0.3f, 0.f);
    s += comask[i] * tr;
  }
  for (int off = 32; off; off >>= 1) s += __shfl_xor(s, off);
  __shared__ float sh[4];
  if ((t & 63) == 0) sh[t >> 6] = s;
  __syncthreads();
  if (t == 0)
    out[(size_t)kB * kC * kHW] = (sh[0] + sh[1] + sh[2] + sh[3]) * (1.f / (float)(kB * kHW));
}

extern "C" void kernel_launch(void* const* d_in, const int* in_sizes, int n_in,
                              void* d_out, int out_size, void* d_ws, size_t ws_size,
                              hipStream_t stream) {
  const float* fv = (const float*)d_in[0];
  const float* ft = (const float*)d_in[1];
  const float* qw = (const float*)d_in[4];
  const float* qb = (const float*)d_in[5];
  const float* kw = (const float*)d_in[6];
  const float* kb = (const float*)d_in[7];
  const int* pos_idx = (const int*)d_in[8];
  const int* neg_idx = (const int*)d_in[9];
  float* out = (float*)d_out;

  // ws layout: fq 37.75M | fk 37.75M | region3 37.75M = {wtq|wtk} then {pr fp32 21.2M | prb bf16 10.6M} | small
  constexpr size_t kFQ = (size_t)kB * kCQ * kHW;
  float* ws   = (float*)d_ws;
  float* fq   = ws;
  float* fk   = fq + kFQ;
  unsigned short* wtq = (unsigned short*)(fk + kFQ);
  unsigned short* wtk = wtq + (size_t)9 * kCQ * kC;
  float* pr   = (float*)wtq;                               // alias, live after convs
  unsigned short* prb = (unsigned short*)(pr + (size_t)kB * kHW * kHW);
  float* maskb   = (float*)(wtk + (size_t)9 * kCQ * kC);
  float* qinv    = maskb + kB * kHW;
  float* kinv    = qinv + kB * kHW;
  float* comaskb = kinv + kB * kHW;
  float* dap     = comaskb + kB * kHW;
  float* dan     = dap + kB * kHW;
  if (ws_size < (size_t)113688576) return;

  zero_kernel<<<dim3((2 * kB * kHW + 255) / 256), 256, 0, stream>>>(dap, 2 * kB * kHW);
  mask_kernel<<<dim3(kB), 320, 0, stream>>>(fv, ft, maskb);
  prep_w_kernel<<<dim3(kCQ, 2), 256, 0, stream>>>(qw, kw, wtq, wtk);
  conv_mfma_kernel<<<dim3(256), 512, 0, stream>>>(wtq, qb, fv, ft, fq);
  conv_mfma_kernel<<<dim3(256), 512, 0, stream>>>(wtk, kb, fv, ft, fk);
  norminv_kernel<<<dim3(kB, 2), 320, 0, stream>>>(fq, fk, qinv, kinv);

  // positive branch (pr/prb overwrite wt region — weights dead now)
  sim_kernel<<<dim3(9, kB), 320, 0, stream>>>(fq, fk, qinv, kinv, pos_idx, pr);
  softmax_kernel<<<dim3(kB * kHW), 320, 0, stream>>>(pr, prb, 1);
  comask_kernel<<<dim3(kB), 320, 0, stream>>>(pr, maskb, pos_idx, comaskb);
  warp_mfma_kernel<<<dim3(16, kB), 512, 0, stream>>>(fv, ft, prb, maskb, pos_idx, out, dap, 1);

  // negative branch
  sim_kernel<<<dim3(9, kB), 320, 0, stream>>>(fq, fk, qinv, kinv, neg_idx, pr);
  softmax_kernel<<<dim3(kB * kHW), 320, 0, stream>>>(pr, prb, 0);
  warp_mfma_kernel<<<dim3(16, kB), 512, 0, stream>>>(fv, ft, prb, maskb, neg_idx, out, dan, 0);

  loss_kernel<<<dim3(1), 256, 0, stream>>>(dap, dan, comaskb, out);
}